// Round 1
// baseline (192.168 us; speedup 1.0000x reference)
//
#include <hip/hip_runtime.h>
#include <math.h>

#define LL 16384
#define Dm 768
#define Hm 1024

// ws layout (float offsets)
#define WS_DOTS  0                       // 16384
#define WS_STATS 16384                   // 2: [max, 1/sum]
#define WS_GI    16400                   // 3072
#define WS_GH    19472                   // 3072
#define WS_PART  24576                   // 512*1024
#define WS_PART2 (24576 + 512*1024)      // 16*1024

__device__ __forceinline__ float dot4(float4 a, float4 b) {
    return a.x*b.x + a.y*b.y + a.z*b.z + a.w*b.w;
}

// Kernel A: blocks [0,1024): dots[row] = text_s[row] . text_v  (wave per 4 rows)
//           blocks [1024,1216): gi[k] = text_v . W_ih[k][off:off+768] + b_ih[k]
//           blocks [1216,1408): gh[k] = h . W_hh[k] + b_hh[k]
__global__ __launch_bounds__(256) void k_dots_gigh(
    const float* __restrict__ text_v, const float* __restrict__ result,
    const float* __restrict__ text_s, const float* __restrict__ hidden_s,
    const float* __restrict__ W_ih, const float* __restrict__ W_hh,
    const float* __restrict__ b_ih, const float* __restrict__ b_hh,
    float* __restrict__ ws)
{
    const int tid  = threadIdx.x;
    const int lane = tid & 63;
    const int wv   = tid >> 6;
    const int b    = blockIdx.x;

    if (b < 1024) {
        // ---- dots over text_s ----
        const int wave_g = b*4 + wv;
        float4 tv0 = *(const float4*)(text_v + 4*lane);
        float4 tv1 = *(const float4*)(text_v + 4*lane + 256);
        float4 tv2 = *(const float4*)(text_v + 4*lane + 512);
        #pragma unroll
        for (int r = 0; r < 4; ++r) {
            const int row = wave_g*4 + r;
            const float* p = text_s + (size_t)row*Dm + 4*lane;
            float4 x0 = *(const float4*)(p);
            float4 x1 = *(const float4*)(p + 256);
            float4 x2 = *(const float4*)(p + 512);
            float s = dot4(x0, tv0) + dot4(x1, tv1) + dot4(x2, tv2);
            #pragma unroll
            for (int o = 32; o; o >>= 1) s += __shfl_xor(s, o);
            if (lane == 0) ws[WS_DOTS + row] = s;
        }
    } else if (b < 1216) {
        // ---- gi ----
        const int wave_g = (b - 1024)*4 + wv;           // 0..767
        const int off = (result[0] >= 0.5f) ? 0 : Dm;
        float4 tv0 = *(const float4*)(text_v + 4*lane);
        float4 tv1 = *(const float4*)(text_v + 4*lane + 256);
        float4 tv2 = *(const float4*)(text_v + 4*lane + 512);
        #pragma unroll
        for (int r = 0; r < 4; ++r) {
            const int k = wave_g*4 + r;                 // 0..3071
            const float* p = W_ih + (size_t)k*(2*Dm) + off + 4*lane;
            float4 x0 = *(const float4*)(p);
            float4 x1 = *(const float4*)(p + 256);
            float4 x2 = *(const float4*)(p + 512);
            float s = dot4(x0, tv0) + dot4(x1, tv1) + dot4(x2, tv2);
            #pragma unroll
            for (int o = 32; o; o >>= 1) s += __shfl_xor(s, o);
            if (lane == 0) ws[WS_GI + k] = s + b_ih[k];
        }
    } else {
        // ---- gh ----
        const int wave_g = (b - 1216)*4 + wv;           // 0..767
        const float* h = hidden_s + (size_t)(LL - 1)*Hm;
        float4 h0 = *(const float4*)(h + 4*lane);
        float4 h1 = *(const float4*)(h + 4*lane + 256);
        float4 h2 = *(const float4*)(h + 4*lane + 512);
        float4 h3 = *(const float4*)(h + 4*lane + 768);
        #pragma unroll
        for (int r = 0; r < 4; ++r) {
            const int k = wave_g*4 + r;                 // 0..3071
            const float* p = W_hh + (size_t)k*Hm + 4*lane;
            float4 x0 = *(const float4*)(p);
            float4 x1 = *(const float4*)(p + 256);
            float4 x2 = *(const float4*)(p + 512);
            float4 x3 = *(const float4*)(p + 768);
            float s = dot4(x0, h0) + dot4(x1, h1) + dot4(x2, h2) + dot4(x3, h3);
            #pragma unroll
            for (int o = 32; o; o >>= 1) s += __shfl_xor(s, o);
            if (lane == 0) ws[WS_GH + k] = s + b_hh[k];
        }
    }
}

// Kernel B: softmax stats (max + 1/sum of exp) over dots[16384]
__global__ __launch_bounds__(1024) void k_stats(float* __restrict__ ws) {
    __shared__ float red[16];
    __shared__ float s_m;
    const int tid = threadIdx.x;
    const float* dots = ws + WS_DOTS;
    float v[16];
    float m = -1e30f;
    #pragma unroll
    for (int k = 0; k < 16; ++k) { v[k] = dots[tid + k*1024]; m = fmaxf(m, v[k]); }
    #pragma unroll
    for (int o = 32; o; o >>= 1) m = fmaxf(m, __shfl_xor(m, o));
    if ((tid & 63) == 0) red[tid >> 6] = m;
    __syncthreads();
    if (tid == 0) {
        float mm = red[0];
        #pragma unroll
        for (int i = 1; i < 16; ++i) mm = fmaxf(mm, red[i]);
        s_m = mm;
    }
    __syncthreads();
    m = s_m;
    float s = 0.f;
    #pragma unroll
    for (int k = 0; k < 16; ++k) s += expf(v[k] - m);
    #pragma unroll
    for (int o = 32; o; o >>= 1) s += __shfl_xor(s, o);
    if ((tid & 63) == 0) red[tid >> 6] = s;
    __syncthreads();
    if (tid == 0) {
        float ss = 0.f;
        #pragma unroll
        for (int i = 0; i < 16; ++i) ss += red[i];
        ws[WS_STATS]     = s_m;
        ws[WS_STATS + 1] = 1.0f / ss;
    }
}

// Kernel C: partial weighted sums of hidden_s rows. Block p: rows [p*32, p*32+32)
__global__ __launch_bounds__(256) void k_wsum(
    const float* __restrict__ hidden_s, float* __restrict__ ws)
{
    const int p = blockIdx.x;            // 0..511
    const int t = threadIdx.x;           // cols 4t..4t+3
    const float m   = ws[WS_STATS];
    const float inv = ws[WS_STATS + 1];
    float4 acc = {0.f, 0.f, 0.f, 0.f};
    const int row0 = p*32;
    for (int r = 0; r < 32; ++r) {
        const int row = row0 + r;
        const float w = expf(ws[WS_DOTS + row] - m) * inv;
        const float4 hv = *(const float4*)(hidden_s + (size_t)row*Hm + 4*t);
        acc.x += w*hv.x; acc.y += w*hv.y; acc.z += w*hv.z; acc.w += w*hv.w;
    }
    *(float4*)(ws + WS_PART + p*1024 + 4*t) = acc;
}

// Kernel D: reduce 512 partials -> 16 partials
__global__ __launch_bounds__(256) void k_reduce(float* __restrict__ ws) {
    const int b = blockIdx.x;            // 0..15
    const int t = threadIdx.x;
    float4 acc = {0.f, 0.f, 0.f, 0.f};
    for (int r = 0; r < 32; ++r) {
        const float4 v = *(const float4*)(ws + WS_PART + (size_t)(b*32 + r)*1024 + 4*t);
        acc.x += v.x; acc.y += v.y; acc.z += v.z; acc.w += v.w;
    }
    *(float4*)(ws + WS_PART2 + b*1024 + 4*t) = acc;
}

// Kernel E: final attn reduce + score + GRU
__global__ __launch_bounds__(1024) void k_final(
    const float* __restrict__ text_v, const float* __restrict__ hidden_s,
    const float* __restrict__ score_W, const float* __restrict__ score_b,
    float* __restrict__ ws, float* __restrict__ out)
{
    __shared__ float sred[16];
    const int tid = threadIdx.x;         // 0..1023 == column
    // attn_h[tid]
    float a = 0.f;
    #pragma unroll
    for (int r = 0; r < 16; ++r) a += ws[WS_PART2 + r*1024 + tid];
    // score = text_v . sW[0:768] + attn_h . sW[768:1792] + b
    float sp = a * score_W[Dm + tid];
    if (tid < Dm) sp += text_v[tid] * score_W[tid];
    #pragma unroll
    for (int o = 32; o; o >>= 1) sp += __shfl_xor(sp, o);
    if ((tid & 63) == 0) sred[tid >> 6] = sp;
    __syncthreads();
    if (tid == 0) {
        float s = score_b[0];
        #pragma unroll
        for (int i = 0; i < 16; ++i) s += sred[i];
        out[0] = s;
    }
    // GRU
    const float gi_r = ws[WS_GI + tid];
    const float gi_z = ws[WS_GI + 1024 + tid];
    const float gi_n = ws[WS_GI + 2048 + tid];
    const float gh_r = ws[WS_GH + tid];
    const float gh_z = ws[WS_GH + 1024 + tid];
    const float gh_n = ws[WS_GH + 2048 + tid];
    const float hprev = hidden_s[(size_t)(LL - 1)*Hm + tid];
    const float r = 1.f / (1.f + expf(-(gi_r + gh_r)));
    const float z = 1.f / (1.f + expf(-(gi_z + gh_z)));
    const float n = tanhf(gi_n + r*gh_n);
    out[1 + tid] = (1.f - z)*n + z*hprev;
}

extern "C" void kernel_launch(void* const* d_in, const int* in_sizes, int n_in,
                              void* d_out, int out_size, void* d_ws, size_t ws_size,
                              hipStream_t stream) {
    const float* text_v   = (const float*)d_in[0];
    const float* result   = (const float*)d_in[1];
    const float* text_s   = (const float*)d_in[2];
    const float* hidden_s = (const float*)d_in[3];
    const float* W_ih     = (const float*)d_in[4];
    const float* W_hh     = (const float*)d_in[5];
    const float* b_ih     = (const float*)d_in[6];
    const float* b_hh     = (const float*)d_in[7];
    const float* score_W  = (const float*)d_in[8];
    const float* score_b  = (const float*)d_in[9];
    float* out = (float*)d_out;
    float* ws  = (float*)d_ws;

    k_dots_gigh<<<1408, 256, 0, stream>>>(text_v, result, text_s, hidden_s,
                                          W_ih, W_hh, b_ih, b_hh, ws);
    k_stats <<<1,   1024, 0, stream>>>(ws);
    k_wsum  <<<512, 256,  0, stream>>>(hidden_s, ws);
    k_reduce<<<16,  256,  0, stream>>>(ws);
    k_final <<<1,   1024, 0, stream>>>(text_v, hidden_s, score_W, score_b, ws, out);
}